// Round 6
// baseline (59.310 us; speedup 1.0000x reference)
//
#include <hip/hip_runtime.h>
#include <math.h>

// Cox partial likelihood NLL.
// loss = -(1/n) * sum_i e_i * (risk_i - log(P[time_i]))
//   where P[t] = sum_{t' <= t} S[t'],  S[t] = sum_{time_j = t} exp(risk_j)
// Decompose: A = sum_i e_i*risk_i ; B = sum_t E[t]*log(P[t]), E[t] = sum_{time_j=t} e_j
// loss = -(A - B)/n
//
// R6: LDS-privatized histogram. Sorted times => a block's 16K-elem chunk spans
// ~98 buckets; private Sl/El[2048] in LDS absorbs all run-piece flushes via
// ds_add_f32 (lgkmcnt domain -- no global atomics in the load/vmcnt stream).
// No cross-lane shuffles in the hot path at all. Global atomic flush once per
// block at the end (~200 atomics, overflow-guarded). 1024 blocks, register
// double-buffered windows (loads of w+1 issue before processing w).

#define TMAXV   100000
#define NPAD    100352          // 98 * 1024, padded bucket count
#define NBLK_SC 98
#define VPT     16              // elements per thread per window
#define NW      4               // windows per block
#define NBLK1   1024            // k1 grid (1024 * 4 * 256 * 16 = 16,777,216)
#define RANGE   2048            // LDS histogram span (buckets)
#define SENT    0x7fffffff      // sentinel time for invalid lanes (never flushed)

__device__ __forceinline__ void atomAddF(float* p, float v) {
    unsafeAtomicAdd(p, v);      // native global_atomic_add_f32
}

// Block reduce (up to 16 waves). Result valid in lane 0 of wave 0 only.
__device__ __forceinline__ float block_reduce_sum(float v, float* lds) {
    const int lane = threadIdx.x & 63;
    const int wid  = threadIdx.x >> 6;
    #pragma unroll
    for (int d = 32; d > 0; d >>= 1) v += __shfl_down(v, d);
    __syncthreads();
    if (lane == 0) lds[wid] = v;
    __syncthreads();
    float r = 0.f;
    if (wid == 0) {
        const int nw = (int)(blockDim.x >> 6);
        r = (lane < nw) ? lds[lane] : 0.f;
        #pragma unroll
        for (int d = 8; d > 0; d >>= 1) r += __shfl_down(r, d);
    }
    return r;
}

// Load one window's strip (VPT elems) into registers R/W/T.
// Invalid lanes: R=-1e9 (exp->0), W=0, T=SENT.
#define LOADW(wi, R, W, T)                                                     \
    do {                                                                       \
        const int base_ = start + (wi) * (256 * VPT) + tid * VPT;              \
        if (base_ + VPT <= end_blk) {                                          \
            _Pragma("unroll")                                                  \
            for (int q = 0; q < VPT / 4; ++q) {                                \
                const float4 rr = *(const float4*)(risk + base_ + 4 * q);      \
                const float4 ww = *(const float4*)(ev   + base_ + 4 * q);      \
                const int4   tt = *(const int4*)(tim   + base_ + 4 * q);       \
                R[4*q+0]=rr.x; R[4*q+1]=rr.y; R[4*q+2]=rr.z; R[4*q+3]=rr.w;    \
                W[4*q+0]=ww.x; W[4*q+1]=ww.y; W[4*q+2]=ww.z; W[4*q+3]=ww.w;    \
                T[4*q+0]=tt.x; T[4*q+1]=tt.y; T[4*q+2]=tt.z; T[4*q+3]=tt.w;    \
            }                                                                  \
        } else {                                                               \
            _Pragma("unroll")                                                  \
            for (int j = 0; j < VPT; ++j) {                                    \
                const int i_ = base_ + j;                                      \
                const bool ok_ = (i_ < end_blk);                               \
                R[j] = ok_ ? risk[i_] : -1e9f;                                 \
                W[j] = ok_ ? ev[i_]   : 0.f;                                   \
                T[j] = ok_ ? tim[i_]  : SENT;                                  \
            }                                                                  \
        }                                                                      \
    } while (0)

#define FLUSHP(tt, vv, ww)                                                     \
    do {                                                                       \
        if ((tt) != SENT) {                                                    \
            const unsigned idx_ = (unsigned)((tt) - tbase);                    \
            if (idx_ < RANGE) {                                                \
                atomicAdd(&Sl[idx_], (vv));                                    \
                atomicAdd(&El[idx_], (ww));                                    \
            } else {                                                           \
                atomAddF(&S[(tt)], (vv));                                      \
                atomAddF(&E[(tt)], (ww));                                      \
            }                                                                  \
        }                                                                      \
    } while (0)

// Sequential run-piece pass over one window's registers; flush to LDS hist.
#define PROCW(R, W, T)                                                         \
    do {                                                                       \
        int   cur_t = T[0];                                                    \
        float cur_v = 0.f, cur_w = 0.f;                                        \
        _Pragma("unroll")                                                      \
        for (int j = 0; j < VPT; ++j) {                                        \
            const float ex_ = __expf(R[j]);                                    \
            accA += W[j] * R[j];                                               \
            if (T[j] != cur_t) {                                               \
                FLUSHP(cur_t, cur_v, cur_w);                                   \
                cur_t = T[j]; cur_v = 0.f; cur_w = 0.f;                        \
            }                                                                  \
            cur_v += ex_; cur_w += W[j];                                       \
        }                                                                      \
        FLUSHP(cur_t, cur_v, cur_w);                                           \
    } while (0)

__global__ __launch_bounds__(256)
void k1_bucket(const float* __restrict__ risk, const float* __restrict__ ev,
               const int* __restrict__ tim,
               float* __restrict__ S, float* __restrict__ E,
               float* __restrict__ Apart, int n) {
    __shared__ float Sl[RANGE];
    __shared__ float El[RANGE];
    __shared__ float lds[16];
    __shared__ int   s_tbase;

    const int tid   = (int)threadIdx.x;
    const int start = (int)blockIdx.x * (NW * 256 * VPT);
    int end_blk = start + NW * 256 * VPT;
    if (end_blk > n) end_blk = n;

    for (int j = tid; j < RANGE; j += 256) { Sl[j] = 0.f; El[j] = 0.f; }
    if (tid == 0) s_tbase = tim[start < n ? start : (n - 1)];
    __syncthreads();
    const int tbase = s_tbase;

    float accA = 0.f;

    // double-buffered windows: issue loads for w+1 before processing w
    float rA[VPT], wA[VPT]; int tA[VPT];
    float rB[VPT], wB[VPT]; int tB[VPT];

    LOADW(0, rA, wA, tA);
    LOADW(1, rB, wB, tB);
    PROCW(rA, wA, tA);
    LOADW(2, rA, wA, tA);
    PROCW(rB, wB, tB);
    LOADW(3, rB, wB, tB);
    PROCW(rA, wA, tA);
    PROCW(rB, wB, tB);

    __syncthreads();
    // flush LDS histogram to global (nonzero buckets only)
    for (int j = tid; j < RANGE; j += 256) {
        const float sv = Sl[j];
        const float se = El[j];
        if (sv != 0.f) atomAddF(&S[tbase + j], sv);
        if (se != 0.f) atomAddF(&E[tbase + j], se);
    }

    const float tot = block_reduce_sum(accA, lds);
    if (tid == 0) Apart[blockIdx.x] = tot;
}

// K2: per-1024-chunk partial sums of S.
__global__ __launch_bounds__(256)
void k2_partials(const float* __restrict__ S, float* __restrict__ partials) {
    __shared__ float lds[16];
    const int base = (int)blockIdx.x * 1024;
    float v = 0.f;
    for (int j = (int)threadIdx.x; j < 1024; j += 256) v += S[base + j];
    const float tot = block_reduce_sum(v, lds);
    if (threadIdx.x == 0) partials[blockIdx.x] = tot;
}

// K3: per-chunk inclusive scan of S (+offset), dot with E via log(P) -> B.
__global__ __launch_bounds__(1024)
void k3_scan_dot(const float* __restrict__ S, const float* __restrict__ E,
                 const float* __restrict__ partials, float* __restrict__ Bacc) {
    __shared__ float lds[16];
    __shared__ float wsum[16];
    __shared__ float s_off;
    const int tid  = (int)threadIdx.x;
    const int lane = tid & 63;
    const int wid  = tid >> 6;
    const int base = (int)blockIdx.x * 1024;

    float p = (tid < (int)blockIdx.x) ? partials[tid] : 0.f;
    const float off = block_reduce_sum(p, lds);
    if (tid == 0) s_off = off;
    __syncthreads();
    const float offset = s_off;

    const float x = S[base + tid];
    float s = x;
    #pragma unroll
    for (int d = 1; d < 64; d <<= 1) {
        const float o = __shfl_up(s, d);
        if (lane >= d) s += o;
    }
    if (lane == 63) wsum[wid] = s;
    __syncthreads();
    if (wid == 0) {
        float ws = (lane < 16) ? wsum[lane] : 0.f;
        #pragma unroll
        for (int d = 1; d < 16; d <<= 1) {
            const float o = __shfl_up(ws, d);
            if (lane >= d) ws += o;
        }
        if (lane < 16) wsum[lane] = ws;
    }
    __syncthreads();
    const float incl = s + (wid > 0 ? wsum[wid - 1] : 0.f);
    const float P = offset + incl;

    const float w = E[base + tid];
    const float c = (w != 0.f) ? w * __logf(P) : 0.f;
    const float tot = block_reduce_sum(c, lds);
    if (tid == 0) atomAddF(Bacc, tot);
}

// K4: reduce Apart[NBLK1], combine with B, write loss.
__global__ __launch_bounds__(256)
void k4_final(const float* __restrict__ Apart, const float* __restrict__ B,
              float* __restrict__ out, float inv_n) {
    __shared__ float lds[16];
    float v = 0.f;
    for (int j = (int)threadIdx.x; j < NBLK1; j += 256) v += Apart[j];
    const float tot = block_reduce_sum(v, lds);
    if (threadIdx.x == 0) out[0] = -(tot - B[0]) * inv_n;
}

extern "C" void kernel_launch(void* const* d_in, const int* in_sizes, int n_in,
                              void* d_out, int out_size, void* d_ws, size_t ws_size,
                              hipStream_t stream) {
    const float* risk = (const float*)d_in[0];
    const float* ev   = (const float*)d_in[1];
    const int*   tim  = (const int*)d_in[2];
    float* out = (float*)d_out;
    const int n = in_sizes[0];

    // workspace layout (floats): S[NPAD] | E[NPAD] | partials[128] | Apart[NBLK1] | B
    float* S        = (float*)d_ws;
    float* E        = S + NPAD;
    float* partials = E + NPAD;
    float* Apart    = partials + 128;
    float* B        = Apart + NBLK1;

    hipMemsetAsync(d_ws, 0, (size_t)(2 * NPAD + 128 + NBLK1 + 2) * sizeof(float), stream);

    const int elems_per_block = NW * 256 * VPT;   // 16384
    const int blocks = (n + elems_per_block - 1) / elems_per_block;  // 1024

    hipLaunchKernelGGL(k1_bucket, dim3(blocks), dim3(256), 0, stream,
                       risk, ev, tim, S, E, Apart, n);
    hipLaunchKernelGGL(k2_partials, dim3(NBLK_SC), dim3(256), 0, stream, S, partials);
    hipLaunchKernelGGL(k3_scan_dot, dim3(NBLK_SC), dim3(1024), 0, stream, S, E, partials, B);
    hipLaunchKernelGGL(k4_final, dim3(1), dim3(256), 0, stream, Apart, B, out, 1.0f / (float)n);
}